// Round 4
// baseline (234.774 us; speedup 1.0000x reference)
//
#include <hip/hip_runtime.h>
#include <hip/hip_fp16.h>

// Problem constants (match reference)
constexpr int kHW = 1024 * 1024;
constexpr int kBatch = 4;
constexpr int kChunksPerImage = kHW / 4;            // 262144 = 2^18
constexpr int kNChunk = kBatch * kChunksPerImage;   // 1048576 float4-chunks
constexpr int kM3 = 17 * 17 * 17;                   // 4913 cells

constexpr int kBlock = 512;
constexpr int kGrid  = 1024;                        // 4 blocks/CU on 256 CUs
constexpr int kThreads = kBlock * kGrid;            // 2^19
constexpr int kIters = kNChunk / kThreads;          // exactly 2

__device__ __forceinline__ float h2f_lo(unsigned int u) {
    __half2 h = *reinterpret_cast<__half2*>(&u);
    return __low2float(h);
}

// 1D LUT lerp from pre-paired LDS table: s1[c*64+i] = (l[i], l[i+1])  (fp32, exact)
__device__ __forceinline__ float apply1d(const float2* __restrict__ s1, int c, float v) {
    float xs = v * 63.0f;
    int i0 = (int)xs;
    i0 = min(max(i0, 0), 62);
    float f = xs - (float)i0;
    float2 p = s1[(c << 6) + i0];
    return fmaf(f, p.y - p.x, p.x);
}

struct F3 { float x, y, z; };

// Trilinear from fp16-packed LDS LUT: s3[cell] = {h(c0)|h(c1), h(c2)|0}
__device__ __forceinline__ F3 tri3d(const uint2* __restrict__ s3,
                                    float yr, float yg, float yb) {
    float xr = yr * 16.0f, xg = yg * 16.0f, xb = yb * 16.0f;
    int ir = min((int)xr, 15);
    int ig = min((int)xg, 15);
    int ib = min((int)xb, 15);
    float fr = xr - (float)ir;
    float fg = xg - (float)ig;
    float fb = xb - (float)ib;

    const int cell = (ir * 17 + ig) * 17 + ib;      // db=1, dg=17, dr=289

    auto blerp = [&](const uint2* __restrict__ p) -> F3 {
        uint2 e0 = p[0];
        uint2 e1 = p[1];
        float2 a01 = __half22float2(*reinterpret_cast<__half2*>(&e0.x));
        float  a2  = h2f_lo(e0.y);
        float2 b01 = __half22float2(*reinterpret_cast<__half2*>(&e1.x));
        float  b2  = h2f_lo(e1.y);
        F3 r;
        r.x = fmaf(fb, b01.x - a01.x, a01.x);
        r.y = fmaf(fb, b01.y - a01.y, a01.y);
        r.z = fmaf(fb, b2 - a2, a2);
        return r;
    };

    F3 v00 = blerp(s3 + cell);            // (r0,g0)
    F3 v01 = blerp(s3 + cell + 17);       // (r0,g1)
    F3 v10 = blerp(s3 + cell + 289);      // (r1,g0)
    F3 v11 = blerp(s3 + cell + 306);      // (r1,g1)

    F3 v0, v1, vf;
    v0.x = fmaf(fg, v01.x - v00.x, v00.x);
    v0.y = fmaf(fg, v01.y - v00.y, v00.y);
    v0.z = fmaf(fg, v01.z - v00.z, v00.z);
    v1.x = fmaf(fg, v11.x - v10.x, v10.x);
    v1.y = fmaf(fg, v11.y - v10.y, v10.y);
    v1.z = fmaf(fg, v11.z - v10.z, v10.z);
    vf.x = fmaf(fr, v1.x - v0.x, v0.x);
    vf.y = fmaf(fr, v1.y - v0.y, v0.y);
    vf.z = fmaf(fr, v1.z - v0.z, v0.z);
    return vf;
}

__global__ __launch_bounds__(kBlock, 8) void lut_apply_kernel(
    const float* __restrict__ x,
    const float* __restrict__ lut1d,   // [3][64]
    const float* __restrict__ lut3d,   // [17][17][17][3]
    float* __restrict__ out)
{
    __shared__ uint2  s3[kM3];         // 39,304 B  fp16-packed 3D LUT
    __shared__ float2 s1[3 * 64];      //  1,536 B  fp32 paired 1D LUT
                                       // total 40,840 B -> 4 blocks/CU

    for (int i = threadIdx.x; i < kM3; i += kBlock) {
        float c0 = lut3d[3 * i], c1 = lut3d[3 * i + 1], c2 = lut3d[3 * i + 2];
        __half2 h01 = __floats2half2_rn(c0, c1);
        __half2 h2p = __floats2half2_rn(c2, 0.0f);
        uint2 e;
        e.x = *reinterpret_cast<unsigned int*>(&h01);
        e.y = *reinterpret_cast<unsigned int*>(&h2p);
        s3[i] = e;
    }
    for (int i = threadIdx.x; i < 3 * 64; i += kBlock) {
        int c = i >> 6, j = i & 63;
        float a = lut1d[(c << 6) + j];
        float b = lut1d[(c << 6) + (j < 63 ? j + 1 : 63)];
        s1[i] = make_float2(a, b);
    }
    __syncthreads();

    const int tid = blockIdx.x * kBlock + threadIdx.x;

    // ---- Load phase: all 6 dwordx4 loads issued before any dependent use ----
    float4 rv[kIters], gv[kIters], bv[kIters];
    size_t baseOff[kIters];
    #pragma unroll
    for (int it = 0; it < kIters; ++it) {
        const int q   = tid + it * kThreads;
        const int b   = q >> 18;
        const int rem = q & (kChunksPerImage - 1);
        const size_t base = (size_t)(3 * b) * kHW + 4 * (size_t)rem;
        baseOff[it] = base;
        rv[it] = *(const float4*)(x + base);
        gv[it] = *(const float4*)(x + base + kHW);
        bv[it] = *(const float4*)(x + base + 2 * kHW);
    }

    // ---- Compute + store per iteration ----
    #pragma unroll
    for (int it = 0; it < kIters; ++it) {
        const float rin[4] = {rv[it].x, rv[it].y, rv[it].z, rv[it].w};
        const float gin[4] = {gv[it].x, gv[it].y, gv[it].z, gv[it].w};
        const float bin[4] = {bv[it].x, bv[it].y, bv[it].z, bv[it].w};
        float ro[4], go[4], bo[4];

        #pragma unroll
        for (int k = 0; k < 4; ++k) {
            float yr = apply1d(s1, 0, rin[k]);
            float yg = apply1d(s1, 1, gin[k]);
            float yb = apply1d(s1, 2, bin[k]);
            yr = fminf(fmaxf(yr, 0.0f), 1.0f);
            yg = fminf(fmaxf(yg, 0.0f), 1.0f);
            yb = fminf(fmaxf(yb, 0.0f), 1.0f);

            F3 v = tri3d(s3, yr, yg, yb);
            ro[k] = v.x; go[k] = v.y; bo[k] = v.z;
        }

        const size_t base = baseOff[it];
        *(float4*)(out + base)           = make_float4(ro[0], ro[1], ro[2], ro[3]);
        *(float4*)(out + base + kHW)     = make_float4(go[0], go[1], go[2], go[3]);
        *(float4*)(out + base + 2 * kHW) = make_float4(bo[0], bo[1], bo[2], bo[3]);
    }
}

extern "C" void kernel_launch(void* const* d_in, const int* in_sizes, int n_in,
                              void* d_out, int out_size, void* d_ws, size_t ws_size,
                              hipStream_t stream) {
    const float* x     = (const float*)d_in[0];
    const float* lut1d = (const float*)d_in[1];
    const float* lut3d = (const float*)d_in[2];
    float* out = (float*)d_out;

    hipLaunchKernelGGL(lut_apply_kernel, dim3(kGrid), dim3(kBlock), 0, stream,
                       x, lut1d, lut3d, out);
}

// Round 5
// 220.288 us; speedup vs baseline: 1.0658x; 1.0658x over previous
//
#include <hip/hip_runtime.h>
#include <hip/hip_fp16.h>

// Problem constants (match reference)
constexpr int kHW = 1024 * 1024;
constexpr int kChunksPerImage = kHW / 4;            // 262144 = 2^18
constexpr int kM3 = 17 * 17 * 17;                   // 4913 cells

constexpr int kBlock = 512;
constexpr int kGrid  = 2048;                        // 1 chunk per thread, exactly covers 4*2^18

__device__ __forceinline__ float h2f_lo(unsigned int u) {
    __half2 h = *reinterpret_cast<__half2*>(&u);
    return __low2float(h);
}

// 1D LUT lerp from pre-paired LDS table: s1[c*64+i] = (l[i], l[i+1])  (fp32, exact)
__device__ __forceinline__ float apply1d(const float2* __restrict__ s1, int c, float v) {
    float xs = v * 63.0f;
    int i0 = (int)xs;
    i0 = min(max(i0, 0), 62);
    float f = xs - (float)i0;
    float2 p = s1[(c << 6) + i0];
    return fmaf(f, p.y - p.x, p.x);
}

struct F3 { float x, y, z; };

// Trilinear from fp16-packed LDS LUT: s3[cell] = {h(c0)|h(c1), h(c2)|0}
__device__ __forceinline__ F3 tri3d(const uint2* __restrict__ s3,
                                    float yr, float yg, float yb) {
    float xr = yr * 16.0f, xg = yg * 16.0f, xb = yb * 16.0f;
    int ir = min((int)xr, 15);
    int ig = min((int)xg, 15);
    int ib = min((int)xb, 15);
    float fr = xr - (float)ir;
    float fg = xg - (float)ig;
    float fb = xb - (float)ib;

    const int cell = (ir * 17 + ig) * 17 + ib;      // db=1, dg=17, dr=289

    auto blerp = [&](const uint2* __restrict__ p) -> F3 {
        uint2 e0 = p[0];
        uint2 e1 = p[1];
        float2 a01 = __half22float2(*reinterpret_cast<__half2*>(&e0.x));
        float  a2  = h2f_lo(e0.y);
        float2 b01 = __half22float2(*reinterpret_cast<__half2*>(&e1.x));
        float  b2  = h2f_lo(e1.y);
        F3 r;
        r.x = fmaf(fb, b01.x - a01.x, a01.x);
        r.y = fmaf(fb, b01.y - a01.y, a01.y);
        r.z = fmaf(fb, b2 - a2, a2);
        return r;
    };

    F3 v00 = blerp(s3 + cell);            // (r0,g0)
    F3 v01 = blerp(s3 + cell + 17);       // (r0,g1)
    F3 v10 = blerp(s3 + cell + 289);      // (r1,g0)
    F3 v11 = blerp(s3 + cell + 306);      // (r1,g1)

    F3 v0, v1, vf;
    v0.x = fmaf(fg, v01.x - v00.x, v00.x);
    v0.y = fmaf(fg, v01.y - v00.y, v00.y);
    v0.z = fmaf(fg, v01.z - v00.z, v00.z);
    v1.x = fmaf(fg, v11.x - v10.x, v10.x);
    v1.y = fmaf(fg, v11.y - v10.y, v10.y);
    v1.z = fmaf(fg, v11.z - v10.z, v10.z);
    vf.x = fmaf(fr, v1.x - v0.x, v0.x);
    vf.y = fmaf(fr, v1.y - v0.y, v0.y);
    vf.z = fmaf(fr, v1.z - v0.z, v0.z);
    return vf;
}

__global__ __launch_bounds__(kBlock, 8) void lut_apply_kernel(
    const float* __restrict__ x,
    const float* __restrict__ lut1d,   // [3][64]
    const float* __restrict__ lut3d,   // [17][17][17][3]
    float* __restrict__ out)
{
    __shared__ uint2  s3[kM3];         // 39,304 B  fp16-packed 3D LUT
    __shared__ float2 s1[3 * 64];      //  1,536 B  fp32 paired 1D LUT
                                       // total 40,840 B -> 4 blocks/CU

    for (int i = threadIdx.x; i < kM3; i += kBlock) {
        float c0 = lut3d[3 * i], c1 = lut3d[3 * i + 1], c2 = lut3d[3 * i + 2];
        __half2 h01 = __floats2half2_rn(c0, c1);
        __half2 h2p = __floats2half2_rn(c2, 0.0f);
        uint2 e;
        e.x = *reinterpret_cast<unsigned int*>(&h01);
        e.y = *reinterpret_cast<unsigned int*>(&h2p);
        s3[i] = e;
    }
    for (int i = threadIdx.x; i < 3 * 64; i += kBlock) {
        int c = i >> 6, j = i & 63;
        float a = lut1d[(c << 6) + j];
        float b = lut1d[(c << 6) + (j < 63 ? j + 1 : 63)];
        s1[i] = make_float2(a, b);
    }
    __syncthreads();

    // Exactly one float4-chunk per thread; grid covers the whole tensor.
    const int q   = blockIdx.x * kBlock + threadIdx.x;   // [0, 2^20)
    const int b   = q >> 18;                             // image index
    const int rem = q & (kChunksPerImage - 1);           // chunk within image
    const size_t base = (size_t)(3 * b) * kHW + 4 * (size_t)rem;

    const float4 r4 = *(const float4*)(x + base);
    const float4 g4 = *(const float4*)(x + base + kHW);
    const float4 b4 = *(const float4*)(x + base + 2 * kHW);

    const float rin[4] = {r4.x, r4.y, r4.z, r4.w};
    const float gin[4] = {g4.x, g4.y, g4.z, g4.w};
    const float bin[4] = {b4.x, b4.y, b4.z, b4.w};
    float ro[4], go[4], bo[4];

    #pragma unroll
    for (int k = 0; k < 4; ++k) {
        float yr = apply1d(s1, 0, rin[k]);
        float yg = apply1d(s1, 1, gin[k]);
        float yb = apply1d(s1, 2, bin[k]);
        yr = fminf(fmaxf(yr, 0.0f), 1.0f);
        yg = fminf(fmaxf(yg, 0.0f), 1.0f);
        yb = fminf(fmaxf(yb, 0.0f), 1.0f);

        F3 v = tri3d(s3, yr, yg, yb);
        ro[k] = v.x; go[k] = v.y; bo[k] = v.z;
    }

    *(float4*)(out + base)           = make_float4(ro[0], ro[1], ro[2], ro[3]);
    *(float4*)(out + base + kHW)     = make_float4(go[0], go[1], go[2], go[3]);
    *(float4*)(out + base + 2 * kHW) = make_float4(bo[0], bo[1], bo[2], bo[3]);
}

extern "C" void kernel_launch(void* const* d_in, const int* in_sizes, int n_in,
                              void* d_out, int out_size, void* d_ws, size_t ws_size,
                              hipStream_t stream) {
    const float* x     = (const float*)d_in[0];
    const float* lut1d = (const float*)d_in[1];
    const float* lut3d = (const float*)d_in[2];
    float* out = (float*)d_out;

    hipLaunchKernelGGL(lut_apply_kernel, dim3(kGrid), dim3(kBlock), 0, stream,
                       x, lut1d, lut3d, out);
}

// Round 6
// 114.767 us; speedup vs baseline: 2.0457x; 1.9194x over previous
//
#include <hip/hip_runtime.h>
#include <hip/hip_fp16.h>

// Problem constants (match reference)
constexpr int kHW = 1024 * 1024;
constexpr int kChunksPerImage = kHW / 4;            // 262144 = 2^18
constexpr int kM3 = 17 * 17 * 17;                   // 4913 cells

constexpr int kBlock = 512;
constexpr int kGrid  = 2048;                        // 1 chunk per thread, exactly covers 4*2^18

__device__ __forceinline__ float h2f_lo(unsigned int u) {
    __half2 h = *reinterpret_cast<__half2*>(&u);
    return __low2float(h);
}

// 1D LUT lerp from pre-paired LDS table: s1[c*64+i] = (l[i], l[i+1])  (fp32, exact)
__device__ __forceinline__ float apply1d(const float2* __restrict__ s1, int c, float v) {
    float xs = v * 63.0f;
    int i0 = (int)xs;
    i0 = min(max(i0, 0), 62);
    float f = xs - (float)i0;
    float2 p = s1[(c << 6) + i0];
    return fmaf(f, p.y - p.x, p.x);
}

struct F3 { float x, y, z; };

// Trilinear from fp16-packed LDS LUT: s3[cell] = {h(c0)|h(c1), h(c2)|0}
__device__ __forceinline__ F3 tri3d(const uint2* __restrict__ s3,
                                    float yr, float yg, float yb) {
    float xr = yr * 16.0f, xg = yg * 16.0f, xb = yb * 16.0f;
    int ir = min((int)xr, 15);
    int ig = min((int)xg, 15);
    int ib = min((int)xb, 15);
    float fr = xr - (float)ir;
    float fg = xg - (float)ig;
    float fb = xb - (float)ib;

    const int cell = (ir * 17 + ig) * 17 + ib;      // db=1, dg=17, dr=289

    auto blerp = [&](const uint2* __restrict__ p) -> F3 {
        uint2 e0 = p[0];
        uint2 e1 = p[1];
        float2 a01 = __half22float2(*reinterpret_cast<__half2*>(&e0.x));
        float  a2  = h2f_lo(e0.y);
        float2 b01 = __half22float2(*reinterpret_cast<__half2*>(&e1.x));
        float  b2  = h2f_lo(e1.y);
        F3 r;
        r.x = fmaf(fb, b01.x - a01.x, a01.x);
        r.y = fmaf(fb, b01.y - a01.y, a01.y);
        r.z = fmaf(fb, b2 - a2, a2);
        return r;
    };

    F3 v00 = blerp(s3 + cell);            // (r0,g0)
    F3 v01 = blerp(s3 + cell + 17);       // (r0,g1)
    F3 v10 = blerp(s3 + cell + 289);      // (r1,g0)
    F3 v11 = blerp(s3 + cell + 306);      // (r1,g1)

    F3 v0, v1, vf;
    v0.x = fmaf(fg, v01.x - v00.x, v00.x);
    v0.y = fmaf(fg, v01.y - v00.y, v00.y);
    v0.z = fmaf(fg, v01.z - v00.z, v00.z);
    v1.x = fmaf(fg, v11.x - v10.x, v10.x);
    v1.y = fmaf(fg, v11.y - v10.y, v10.y);
    v1.z = fmaf(fg, v11.z - v10.z, v10.z);
    vf.x = fmaf(fr, v1.x - v0.x, v0.x);
    vf.y = fmaf(fr, v1.y - v0.y, v0.y);
    vf.z = fmaf(fr, v1.z - v0.z, v0.z);
    return vf;
}

// NOTE: no min-waves occupancy bound. R4/R5 showed __launch_bounds__(512, 8)
// capped the allocator at 32 VGPRs -> massive scratch spill (FETCH 3.5x,
// WRITE 6.3x, kernel 142 us). Let the allocator size freely; LDS (40.8 KB)
// still allows up to 4 blocks/CU.
__global__ __launch_bounds__(kBlock) void lut_apply_kernel(
    const float* __restrict__ x,
    const float* __restrict__ lut1d,   // [3][64]
    const float* __restrict__ lut3d,   // [17][17][17][3]
    float* __restrict__ out)
{
    __shared__ uint2  s3[kM3];         // 39,304 B  fp16-packed 3D LUT
    __shared__ float2 s1[3 * 64];      //  1,536 B  fp32 paired 1D LUT

    for (int i = threadIdx.x; i < kM3; i += kBlock) {
        float c0 = lut3d[3 * i], c1 = lut3d[3 * i + 1], c2 = lut3d[3 * i + 2];
        __half2 h01 = __floats2half2_rn(c0, c1);
        __half2 h2p = __floats2half2_rn(c2, 0.0f);
        uint2 e;
        e.x = *reinterpret_cast<unsigned int*>(&h01);
        e.y = *reinterpret_cast<unsigned int*>(&h2p);
        s3[i] = e;
    }
    for (int i = threadIdx.x; i < 3 * 64; i += kBlock) {
        int c = i >> 6, j = i & 63;
        float a = lut1d[(c << 6) + j];
        float b = lut1d[(c << 6) + (j < 63 ? j + 1 : 63)];
        s1[i] = make_float2(a, b);
    }
    __syncthreads();

    // Exactly one float4-chunk per thread; grid covers the whole tensor.
    const int q   = blockIdx.x * kBlock + threadIdx.x;   // [0, 2^20)
    const int b   = q >> 18;                             // image index
    const int rem = q & (kChunksPerImage - 1);           // chunk within image
    const size_t base = (size_t)(3 * b) * kHW + 4 * (size_t)rem;

    const float4 r4 = *(const float4*)(x + base);
    const float4 g4 = *(const float4*)(x + base + kHW);
    const float4 b4 = *(const float4*)(x + base + 2 * kHW);

    const float rin[4] = {r4.x, r4.y, r4.z, r4.w};
    const float gin[4] = {g4.x, g4.y, g4.z, g4.w};
    const float bin[4] = {b4.x, b4.y, b4.z, b4.w};
    float ro[4], go[4], bo[4];

    #pragma unroll
    for (int k = 0; k < 4; ++k) {
        float yr = apply1d(s1, 0, rin[k]);
        float yg = apply1d(s1, 1, gin[k]);
        float yb = apply1d(s1, 2, bin[k]);
        yr = fminf(fmaxf(yr, 0.0f), 1.0f);
        yg = fminf(fmaxf(yg, 0.0f), 1.0f);
        yb = fminf(fmaxf(yb, 0.0f), 1.0f);

        F3 v = tri3d(s3, yr, yg, yb);
        ro[k] = v.x; go[k] = v.y; bo[k] = v.z;
    }

    *(float4*)(out + base)           = make_float4(ro[0], ro[1], ro[2], ro[3]);
    *(float4*)(out + base + kHW)     = make_float4(go[0], go[1], go[2], go[3]);
    *(float4*)(out + base + 2 * kHW) = make_float4(bo[0], bo[1], bo[2], bo[3]);
}

extern "C" void kernel_launch(void* const* d_in, const int* in_sizes, int n_in,
                              void* d_out, int out_size, void* d_ws, size_t ws_size,
                              hipStream_t stream) {
    const float* x     = (const float*)d_in[0];
    const float* lut1d = (const float*)d_in[1];
    const float* lut3d = (const float*)d_in[2];
    float* out = (float*)d_out;

    hipLaunchKernelGGL(lut_apply_kernel, dim3(kGrid), dim3(kBlock), 0, stream,
                       x, lut1d, lut3d, out);
}

// Round 7
// 108.668 us; speedup vs baseline: 2.1605x; 1.0561x over previous
//
#include <hip/hip_runtime.h>
#include <hip/hip_fp16.h>

// Problem constants (match reference)
constexpr int kHW = 1024 * 1024;
constexpr int kChunksPerImage = kHW / 4;            // 262144 = 2^18
constexpr int kM3 = 17 * 17 * 17;                   // 4913 cells

// Packed-table layout in d_ws (uints):
//   [0,      4928)  pA[cell] = fp16(c0) | fp16(c1)<<16
//   [4928,   9856)  pB[cell] = fp16(c2[cell]) | fp16(c2[cell+1])<<16
//   [9856,  10048)  p1[c*64+j] = fp16(l[j]) | fp16(l[j+1])<<16
constexpr int kPA   = 4928;                         // padded table stride
constexpr int kLdsU = 2 * kPA;                      // 9856 uints -> 39,424 B in LDS
constexpr int kP1   = kLdsU;                        // 1D table offset in ws

constexpr int kBlock = 512;
constexpr int kGrid  = 2048;                        // 1 float4-chunk per thread

__device__ __forceinline__ float2 h2f2(unsigned int u) {
    return __half22float2(*reinterpret_cast<__half2*>(&u));
}
__device__ __forceinline__ unsigned int packh2(float a, float b) {
    __half2 h = __floats2half2_rn(a, b);
    return *reinterpret_cast<unsigned int*>(&h);
}

// ---------------- pre-pass: build packed tables in d_ws ----------------
__global__ void pack_kernel(const float* __restrict__ lut1d,
                            const float* __restrict__ lut3d,
                            unsigned int* __restrict__ ws) {
    const int i = blockIdx.x * 256 + threadIdx.x;   // 64 blocks x 256 = 16384
    if (i < kPA) {
        unsigned int a = 0, b = 0;
        if (i < kM3) {
            float c0 = lut3d[3 * i], c1 = lut3d[3 * i + 1], c2 = lut3d[3 * i + 2];
            int j = (i + 1 < kM3) ? i + 1 : i;
            float c2n = lut3d[3 * j + 2];
            a = packh2(c0, c1);
            b = packh2(c2, c2n);
        }
        ws[i]       = a;
        ws[kPA + i] = b;
    }
    if (i < 192) {
        int c = i >> 6, j = i & 63;
        float l0 = lut1d[(c << 6) + j];
        float l1 = lut1d[(c << 6) + (j < 63 ? j + 1 : 63)];
        ws[kP1 + i] = packh2(l0, l1);
    }
}

// 1D LUT lerp: paired fp16 table held in a VGPR per channel, gathered with
// ds_bpermute (conflict-free crossbar, no LDS banks touched).
__device__ __forceinline__ float apply1d_bp(unsigned int treg, float v) {
    float xs = v * 63.0f;
    int i0 = min(max((int)xs, 0), 62);
    float f = xs - (float)i0;
    unsigned int pair =
        (unsigned int)__builtin_amdgcn_ds_bpermute(i0 << 2, (int)treg);
    float2 p = h2f2(pair);
    return fmaf(f, p.y - p.x, p.x);
}

struct F3 { float x, y, z; };

__device__ __forceinline__ F3 tri3d(const unsigned int* __restrict__ sA,
                                    const unsigned int* __restrict__ sB,
                                    float yr, float yg, float yb) {
    float xr = yr * 16.0f, xg = yg * 16.0f, xb = yb * 16.0f;
    int ir = min((int)xr, 15);
    int ig = min((int)xg, 15);
    int ib = min((int)xb, 15);
    float fr = xr - (float)ir;
    float fg = xg - (float)ig;
    float fb = xb - (float)ib;

    const int cell = (ir * 17 + ig) * 17 + ib;      // db=1, dg=17, dr=289

    // Per (r,g) corner pair: ds_read2_b32 (c0,c1 of both b-corners) +
    // ds_read_b32 (paired c2) = 3 bank-words.
    auto corner = [&](int c) -> F3 {
        unsigned int a0 = sA[c];
        unsigned int a1 = sA[c + 1];
        unsigned int bp = sB[c];
        float2 A0 = h2f2(a0), A1 = h2f2(a1), Bc = h2f2(bp);
        F3 r;
        r.x = fmaf(fb, A1.x - A0.x, A0.x);
        r.y = fmaf(fb, A1.y - A0.y, A0.y);
        r.z = fmaf(fb, Bc.y - Bc.x, Bc.x);
        return r;
    };

    F3 v00 = corner(cell);
    F3 v01 = corner(cell + 17);
    F3 v10 = corner(cell + 289);
    F3 v11 = corner(cell + 306);

    F3 v0, v1, vf;
    v0.x = fmaf(fg, v01.x - v00.x, v00.x);
    v0.y = fmaf(fg, v01.y - v00.y, v00.y);
    v0.z = fmaf(fg, v01.z - v00.z, v00.z);
    v1.x = fmaf(fg, v11.x - v10.x, v10.x);
    v1.y = fmaf(fg, v11.y - v10.y, v10.y);
    v1.z = fmaf(fg, v11.z - v10.z, v10.z);
    vf.x = fmaf(fr, v1.x - v0.x, v0.x);
    vf.y = fmaf(fr, v1.y - v0.y, v0.y);
    vf.z = fmaf(fr, v1.z - v0.z, v0.z);
    return vf;
}

// NOTE: no min-waves bound — __launch_bounds__(512,8) forced VGPR=32 and
// caused scratch spill (R4/R5: FETCH 3.5x, WRITE 6.3x, kernel 142 us).
__global__ __launch_bounds__(kBlock) void lut_apply_kernel(
    const float* __restrict__ x,
    const unsigned int* __restrict__ ws,
    float* __restrict__ out)
{
    __shared__ uint4 ldsv[kLdsU / 4];               // 39,424 B -> 4 blocks/CU
    unsigned int* lds = (unsigned int*)ldsv;

    // Flat vectorized fill of the packed 3D tables (pre-packed by pack_kernel).
    const uint4* wsv = (const uint4*)ws;
    #pragma unroll 1
    for (int i = threadIdx.x; i < kLdsU / 4; i += kBlock) ldsv[i] = wsv[i];

    // Per-wave 1D table in registers (lane j holds pair (l[j], l[j+1])).
    const int lane = threadIdx.x & 63;
    const unsigned int t0 = ws[kP1 + lane];
    const unsigned int t1 = ws[kP1 + 64 + lane];
    const unsigned int t2 = ws[kP1 + 128 + lane];
    __syncthreads();

    const unsigned int* sA = lds;
    const unsigned int* sB = lds + kPA;

    // Exactly one float4-chunk per thread.
    const int q   = blockIdx.x * kBlock + threadIdx.x;   // [0, 2^20)
    const int b   = q >> 18;
    const int rem = q & (kChunksPerImage - 1);
    const size_t base = (size_t)(3 * b) * kHW + 4 * (size_t)rem;

    const float4 r4 = *(const float4*)(x + base);
    const float4 g4 = *(const float4*)(x + base + kHW);
    const float4 b4 = *(const float4*)(x + base + 2 * kHW);

    const float rin[4] = {r4.x, r4.y, r4.z, r4.w};
    const float gin[4] = {g4.x, g4.y, g4.z, g4.w};
    const float bin[4] = {b4.x, b4.y, b4.z, b4.w};
    float ro[4], go[4], bo[4];

    #pragma unroll
    for (int k = 0; k < 4; ++k) {
        float yr = apply1d_bp(t0, rin[k]);
        float yg = apply1d_bp(t1, gin[k]);
        float yb = apply1d_bp(t2, bin[k]);
        yr = fminf(fmaxf(yr, 0.0f), 1.0f);
        yg = fminf(fmaxf(yg, 0.0f), 1.0f);
        yb = fminf(fmaxf(yb, 0.0f), 1.0f);

        F3 v = tri3d(sA, sB, yr, yg, yb);
        ro[k] = v.x; go[k] = v.y; bo[k] = v.z;
    }

    *(float4*)(out + base)           = make_float4(ro[0], ro[1], ro[2], ro[3]);
    *(float4*)(out + base + kHW)     = make_float4(go[0], go[1], go[2], go[3]);
    *(float4*)(out + base + 2 * kHW) = make_float4(bo[0], bo[1], bo[2], bo[3]);
}

extern "C" void kernel_launch(void* const* d_in, const int* in_sizes, int n_in,
                              void* d_out, int out_size, void* d_ws, size_t ws_size,
                              hipStream_t stream) {
    const float* x     = (const float*)d_in[0];
    const float* lut1d = (const float*)d_in[1];
    const float* lut3d = (const float*)d_in[2];
    float* out = (float*)d_out;
    unsigned int* ws = (unsigned int*)d_ws;

    hipLaunchKernelGGL(pack_kernel, dim3(64), dim3(256), 0, stream,
                       lut1d, lut3d, ws);
    hipLaunchKernelGGL(lut_apply_kernel, dim3(kGrid), dim3(kBlock), 0, stream,
                       x, ws, out);
}